// Round 2
// baseline (378.200 us; speedup 1.0000x reference)
//
#include <hip/hip_runtime.h>

// ---------------------------------------------------------------------------
// SpatialSelfCrossAttention  (B=32, C=256, H=W=32, N=1024)
// I/O fp32, internal bf16 MFMA (fp32 accum). Verified pipeline (round 4 pass).
//
// Round-7 changes (kattn only):
//  * Software pipeline: body = STAGE(j+1); softmax(j-1); QK(j); PV(j-1); bar.
//    QK(j)'s ds_read+MFMA overlap softmax(j-1) VALU + P LDS round trip;
//    PV(j-1) queues behind QK(j) on the matrix pipe.
//  * V rotated over 3 LDS buffers (consumed one phase later than K; 2-slot
//    rotation would collide with prefetch distance 2). K stays double-buf.
//  * Single S register set (softmax reads S(j-1) before QK(j) overwrites;
//    WAR only) to hold VGPR at 128 (occupancy is 2 waves/SIMD, reg-capped).
//  * LDS: K1 32K + K2 32K + V 48K + Ps 9.2K = 121 KB (1 block/CU).
// ---------------------------------------------------------------------------

typedef unsigned short u16;
typedef __attribute__((ext_vector_type(8))) short bf16x8;
typedef __attribute__((ext_vector_type(4))) float f32x4;

#define MFMA16(a, b, c) __builtin_amdgcn_mfma_f32_16x16x32_bf16((a), (b), (c), 0, 0, 0)

#define NC 262144ull            // 1024*256
#define REG 8388608ull          // 32*NC
#define OFF_X1T  0ull
#define OFF_X2T  (REG)
#define OFF_Q1T  (2ull*REG)
#define OFF_K1T  (3ull*REG)
#define OFF_Q2T  (4ull*REG)
#define OFF_K2T  (5ull*REG)
#define OFF_V    (6ull*REG)
#define OFF_H1T  OFF_X1T
#define OFF_H12T OFF_X2T
#define WS_NEED_BYTES (7ull*REG*2)

__device__ __forceinline__ float b2f(u16 u) {
    union { unsigned int i; float f; } v; v.i = ((unsigned int)u) << 16; return v.f;
}
__device__ __forceinline__ u16 f2b(float f) {
    union { float f; unsigned int i; } v; v.f = f;
    unsigned int r = (v.i + 0x7FFFu + ((v.i >> 16) & 1u)) >> 16;
    return (u16)r;
}

// async global->LDS DMA, 16 B per lane. lptr must be wave-uniform; HW adds
// lane*16. gptr is per-lane.
__device__ __forceinline__ void gload16(const u16* g, u16* l) {
    __builtin_amdgcn_global_load_lds(
        (const __attribute__((address_space(1))) void*)g,
        (__attribute__((address_space(3))) void*)l,
        16, 0, 0);
}

__global__ void ksig(float* out, float val) {
    if (threadIdx.x == 0 && blockIdx.x == 0) out[0] = val;
}

// ---------------------------------------------------------------------------
// ktrans: X[b][c][n] fp32 -> XT[b][n][c] bf16. grid (16,4,64), block 256.
// ---------------------------------------------------------------------------
__global__ __launch_bounds__(256) void ktrans(
    const float* __restrict__ x1, const float* __restrict__ x2, u16* __restrict__ ws)
{
    int nt = blockIdx.x, ct = blockIdx.y, bz = blockIdx.z;
    int b = bz >> 1, which = bz & 1;
    const float* X = (which ? x2 : x1) + (size_t)b * NC;
    u16* XT = ws + (which ? OFF_X2T : OFF_X1T) + (size_t)b * NC;
    int c0 = ct * 64, n0 = nt * 64;

    __shared__ __align__(16) u16 tile[64][68];
    int t = threadIdx.x;
    int tn = t & 15, tc = t >> 4;
#pragma unroll
    for (int j = 0; j < 4; ++j) {
        float4 v = *(const float4*)(X + (size_t)(c0 + 4 * tc + j) * 1024 + n0 + 4 * tn);
        u16* d = &tile[4 * tc + j][4 * tn];
        d[0] = f2b(v.x); d[1] = f2b(v.y); d[2] = f2b(v.z); d[3] = f2b(v.w);
    }
    __syncthreads();
    int tcB = t & 15, tnB = t >> 4;
#pragma unroll
    for (int i = 0; i < 4; ++i) {
        ushort4 o;
        o.x = tile[4 * tcB + 0][4 * tnB + i];
        o.y = tile[4 * tcB + 1][4 * tnB + i];
        o.z = tile[4 * tcB + 2][4 * tnB + i];
        o.w = tile[4 * tcB + 3][4 * tnB + i];
        *(ushort4*)(XT + (size_t)(n0 + 4 * tnB + i) * 256 + c0 + 4 * tcB) = o;
    }
}

// ---------------------------------------------------------------------------
// gemm_core: C[128x128] = A[m][k=256] * B[n][k=256]^T (+bias, +clamped-h,
// +fp32 residual). Verified bit-exact (r3 self-test).
// ---------------------------------------------------------------------------
__device__ __forceinline__ void gemm_core(
    const void* __restrict__ A, int aF32,
    const void* __restrict__ B, int bF32,
    int m0, int n0,
    void* __restrict__ C, int ldc, int cF32,
    const float* __restrict__ bias, int biasPerRow,
    const float* __restrict__ addSrc, int clampH)
{
    __shared__ __align__(16) u16 As[128 * 40];
    __shared__ __align__(16) u16 Bs[128 * 40];
    int t = threadIdx.x;
    int lane = t & 63, wave = t >> 6;
    int wm = wave >> 1, wn = wave & 1;
    int col = lane & 15, quad = lane >> 4;

    f32x4 acc[4][4];
#pragma unroll
    for (int i = 0; i < 4; ++i)
#pragma unroll
        for (int j = 0; j < 4; ++j) acc[i][j] = f32x4{0.f, 0.f, 0.f, 0.f};

    int r1 = t >> 2, c1 = t & 3;
    int r2 = r1 + 64;

    for (int kt = 0; kt < 8; ++kt) {
        int k0 = kt * 32;
        __syncthreads();
        if (aF32) {
            const float* Af = (const float*)A;
#pragma unroll
            for (int pp = 0; pp < 2; ++pp) {
                int r = pp ? r2 : r1;
                float4 v0 = *(const float4*)(Af + (size_t)(m0 + r) * 256 + k0 + c1 * 8);
                float4 v1 = *(const float4*)(Af + (size_t)(m0 + r) * 256 + k0 + c1 * 8 + 4);
                ushort4 o0, o1;
                o0.x = f2b(v0.x); o0.y = f2b(v0.y); o0.z = f2b(v0.z); o0.w = f2b(v0.w);
                o1.x = f2b(v1.x); o1.y = f2b(v1.y); o1.z = f2b(v1.z); o1.w = f2b(v1.w);
                *(ushort4*)&As[r * 40 + c1 * 8] = o0;
                *(ushort4*)&As[r * 40 + c1 * 8 + 4] = o1;
            }
        } else {
            const u16* Ab = (const u16*)A;
            *(uint4*)&As[r1 * 40 + c1 * 8] = *(const uint4*)(Ab + (size_t)(m0 + r1) * 256 + k0 + c1 * 8);
            *(uint4*)&As[r2 * 40 + c1 * 8] = *(const uint4*)(Ab + (size_t)(m0 + r2) * 256 + k0 + c1 * 8);
        }
        if (bF32) {
            const float* Bf = (const float*)B;
#pragma unroll
            for (int pp = 0; pp < 2; ++pp) {
                int r = pp ? r2 : r1;
                float4 v0 = *(const float4*)(Bf + (size_t)(n0 + r) * 256 + k0 + c1 * 8);
                float4 v1 = *(const float4*)(Bf + (size_t)(n0 + r) * 256 + k0 + c1 * 8 + 4);
                ushort4 o0, o1;
                o0.x = f2b(v0.x); o0.y = f2b(v0.y); o0.z = f2b(v0.z); o0.w = f2b(v0.w);
                o1.x = f2b(v1.x); o1.y = f2b(v1.y); o1.z = f2b(v1.z); o1.w = f2b(v1.w);
                *(ushort4*)&Bs[r * 40 + c1 * 8] = o0;
                *(ushort4*)&Bs[r * 40 + c1 * 8 + 4] = o1;
            }
        } else {
            const u16* Bb = (const u16*)B;
            *(uint4*)&Bs[r1 * 40 + c1 * 8] = *(const uint4*)(Bb + (size_t)(n0 + r1) * 256 + k0 + c1 * 8);
            *(uint4*)&Bs[r2 * 40 + c1 * 8] = *(const uint4*)(Bb + (size_t)(n0 + r2) * 256 + k0 + c1 * 8);
        }
        __syncthreads();

        bf16x8 af[4], bf[4];
#pragma unroll
        for (int mf = 0; mf < 4; ++mf)
            af[mf] = *(const bf16x8*)&As[(wm * 64 + mf * 16 + col) * 40 + quad * 8];
#pragma unroll
        for (int nf = 0; nf < 4; ++nf)
            bf[nf] = *(const bf16x8*)&Bs[(wn * 64 + nf * 16 + col) * 40 + quad * 8];
#pragma unroll
        for (int mf = 0; mf < 4; ++mf)
#pragma unroll
            for (int nf = 0; nf < 4; ++nf)
                acc[mf][nf] = MFMA16(af[mf], bf[nf], acc[mf][nf]);
    }

#pragma unroll
    for (int mf = 0; mf < 4; ++mf)
#pragma unroll
        for (int nf = 0; nf < 4; ++nf) {
            int gm = m0 + wm * 64 + mf * 16 + quad * 4;
            int gn = n0 + wn * 64 + nf * 16 + col;
            float bcol = biasPerRow ? 0.f : bias[gn];
#pragma unroll
            for (int r = 0; r < 4; ++r) {
                int row = gm + r;
                float hv = acc[mf][nf][r] + (biasPerRow ? bias[row] : bcol);
                if (clampH) hv = fminf(fmaxf(hv, -0.05f), 0.05f);
                size_t ci = (size_t)row * ldc + gn;
                float v = hv + (addSrc ? addSrc[ci] : 0.f);
                if (cF32) ((float*)C)[ci] = v;
                else ((u16*)C)[ci] = f2b(v);
            }
        }
}

// ---------------------------------------------------------------------------
// kproj: 5 projections per batch. 1-D grid 2560, XCD-clustered, block 256.
//  id<64:  (id>>4): 0 Q1T, 1 K1T, 2 Q2T, 3 K2T -> [1024 n][256 o] bf16
//  id>=64: V[256 o][1024 n] bf16
// ---------------------------------------------------------------------------
__global__ __launch_bounds__(256) void kproj(
    const float* __restrict__ Wq, const float* __restrict__ bq,
    const float* __restrict__ Wk, const float* __restrict__ bk,
    const float* __restrict__ Wv, const float* __restrict__ bv,
    u16* __restrict__ ws)
{
    int blk = blockIdx.x;
    int xcd = blk & 7, jj = blk >> 3;       // jj 0..319
    int bg = jj / 80, id = jj % 80;
    int b = bg * 8 + xcd;                   // batches serialize per XCD
    const u16* X1T = ws + OFF_X1T + (size_t)b * NC;
    const u16* X2T = ws + OFF_X2T + (size_t)b * NC;
    if (id < 64) {
        int out = id >> 4, tt = id & 15, mt = tt >> 1, nt = tt & 1;
        const u16* A = (out < 2) ? X1T : X2T;
        const float* W = (out & 1) ? Wk : Wq;
        const float* bb = (out & 1) ? bk : bq;
        size_t off = (out == 0) ? OFF_Q1T : (out == 1) ? OFF_K1T : (out == 2) ? OFF_Q2T : OFF_K2T;
        u16* C = ws + off + (size_t)b * NC;
        gemm_core(A, 0, W, 1, mt * 128, nt * 128, C, 256, 0, bb, 0, nullptr, 0);
    } else {
        int tt = id - 64, mt = tt >> 3, nt = tt & 7;
        u16* C = ws + OFF_V + (size_t)b * NC;
        gemm_core(Wv, 1, X1T, 0, mt * 128, nt * 128, C, 1024, 0, bv, 1, nullptr, 0);
    }
}

// ---------------------------------------------------------------------------
// kattn v4: grid 256 (XCD-clustered), block 512 = 8 waves x 16 queries.
// Software-pipelined: QK(j) overlaps softmax(j-1)+PV(j-1). Async DMA staging
// (global_load_lds), K double-buffered, V triple-buffered, 1 barrier/iter.
// LDS: K1 32K + K2 32K + V 48K + Ps 9.2K = 121 KB (1 block/CU).
//
// K tile layout (per buffer): [32 key-rows][256 ch] u16, stored byte offset
// within a row XOR'd with ((row&7)<<4). Source addresses pre-swizzled so the
// lane-linear DMA lands data swizzled; reads apply the same XOR.
// V tile layout: [256 ch][32 keys] u16, linear (read pattern already uniform).
// ---------------------------------------------------------------------------
__global__ __launch_bounds__(512, 2) void kattn(u16* __restrict__ ws)
{
    int blk = blockIdx.x;
    int xcd = blk & 7, jj = blk >> 3;        // jj 0..31
    int b = ((jj >> 3) << 3) + xcd;          // 4 batch-groups, serialized per XCD
    int qt = jj & 7;                         // 8 q-tiles of 128 queries
    int t = threadIdx.x, lane = t & 63, wave = t >> 6;   // wave 0..7
    int col = lane & 15, quad = lane >> 4;

    const u16* Q1T = ws + OFF_Q1T + (size_t)b * NC;
    const u16* K1T = ws + OFF_K1T + (size_t)b * NC;
    const u16* Q2T = ws + OFF_Q2T + (size_t)b * NC;
    const u16* K2T = ws + OFF_K2T + (size_t)b * NC;
    const u16* V   = ws + OFF_V   + (size_t)b * NC;
    u16* H1T  = ws + OFF_H1T  + (size_t)b * NC;
    u16* H12T = ws + OFF_H12T + (size_t)b * NC;

    __shared__ __align__(16) u16 K1s[2][8192];   // [buf][32*256]
    __shared__ __align__(16) u16 K2s[2][8192];
    __shared__ __align__(16) u16 Vs[3][8192];    // [buf][256*32]
    __shared__ __align__(16) u16 Ps[8][16 * 36];

    int i0 = qt * 128 + wave * 16;

    // Q fragments in registers: A[m=col][k = f*32 + quad*8 + j]
    bf16x8 aq1[8], aq2[8];
#pragma unroll
    for (int f = 0; f < 8; ++f) {
        aq1[f] = *(const bf16x8*)(Q1T + (size_t)(i0 + col) * 256 + f * 32 + quad * 8);
        aq2[f] = *(const bf16x8*)(Q2T + (size_t)(i0 + col) * 256 + f * 32 + quad * 8);
    }

    f32x4 h1[16], h12[16];
#pragma unroll
    for (int cf = 0; cf < 16; ++cf) { h1[cf] = f32x4{0.f,0.f,0.f,0.f}; h12[cf] = f32x4{0.f,0.f,0.f,0.f}; }
    float l1p[4], l2p[4];
#pragma unroll
    for (int r = 0; r < 4; ++r) { l1p[r] = 0.f; l2p[r] = 0.f; }

    const float sc = 0.0901684400555602f;   // log2(e)/16
    const float SH = 5.770780163555851f;    // 4*log2(e): fixed shift, overflow-safe

    // ---- staging geometry (loop-invariant per thread) ----
    int kr_ = t >> 5;                        // key row, shot 0
    int kwb = (t & 31) << 4;                 // stored byte offset
    int kwl = kwb ^ ((kr_ & 7) << 4);        // logical (source) byte offset
    const u16* k1src = K1T + (size_t)kr_ * 256 + (kwl >> 1);
    const u16* k2src = K2T + (size_t)kr_ * 256 + (kwl >> 1);
    int vrow = t >> 2;                       // channel, shot 0
    int vo = (t & 3) << 3;
    const u16* vsrc = V + (size_t)vrow * 1024 + vo;
    int ldsw = wave * 512;                   // wave-uniform LDS base (u16)

    u16* P = Ps[wave];
    int swz = (col & 7) << 3;                // read-side XOR, u16 units

#define STAGE(jt, ks, vs) do {                                          \
        const u16* s1_ = k1src + (size_t)(jt) * 8192;                   \
        const u16* s2_ = k2src + (size_t)(jt) * 8192;                   \
        const u16* sv_ = vsrc + (size_t)(jt) * 32;                      \
        gload16(s1_,          &K1s[ks][ldsw]);                          \
        gload16(s1_ + 4096,   &K1s[ks][ldsw + 4096]);                   \
        gload16(s2_,          &K2s[ks][ldsw]);                          \
        gload16(s2_ + 4096,   &K2s[ks][ldsw + 4096]);                   \
        gload16(sv_,          &Vs[vs][ldsw]);                           \
        gload16(sv_ + 131072, &Vs[vs][ldsw + 4096]);                    \
    } while (0)

#define QK_T(ks) do {                                                   \
        const u16* K1c_ = K1s[ks];                                      \
        const u16* K2c_ = K2s[ks];                                      \
        s1v[0] = s1v[1] = s2v[0] = s2v[1] = f32x4{0.f,0.f,0.f,0.f};     \
        __builtin_amdgcn_s_setprio(1);                                  \
        _Pragma("unroll")                                               \
        for (int nf = 0; nf < 2; ++nf) {                                \
            int krow_ = nf * 16 + col;                                  \
            _Pragma("unroll")                                           \
            for (int f = 0; f < 8; ++f) {                               \
                int wb_ = (f * 32 + quad * 8) ^ swz;                    \
                bf16x8 bk1_ = *(const bf16x8*)&K1c_[krow_ * 256 + wb_]; \
                s1v[nf] = MFMA16(aq1[f], bk1_, s1v[nf]);                \
                bf16x8 bk2_ = *(const bf16x8*)&K2c_[krow_ * 256 + wb_]; \
                s2v[nf] = MFMA16(aq2[f], bk2_, s2v[nf]);                \
            }                                                           \
        }                                                               \
        __builtin_amdgcn_s_setprio(0);                                  \
    } while (0)

#define SM_T() do {                                                     \
        _Pragma("unroll")                                               \
        for (int r = 0; r < 4; ++r) {                                   \
            float p0_ = __builtin_amdgcn_exp2f(s1v[0][r] * sc - SH);    \
            float p1_ = __builtin_amdgcn_exp2f(s1v[1][r] * sc - SH);    \
            l1p[r] += p0_ + p1_;                                        \
            P[(quad * 4 + r) * 36 + col] = f2b(p0_);                    \
            P[(quad * 4 + r) * 36 + 16 + col] = f2b(p1_);               \
        }                                                               \
        p1f = *(const bf16x8*)&P[col * 36 + quad * 8];                  \
        _Pragma("unroll")                                               \
        for (int r = 0; r < 4; ++r) {                                   \
            float s0_ = s1v[0][r] + s2v[0][r];                          \
            float s1_ = s1v[1][r] + s2v[1][r];                          \
            float p0_ = __builtin_amdgcn_exp2f(s0_ * sc - SH);          \
            float p1_ = __builtin_amdgcn_exp2f(s1_ * sc - SH);          \
            l2p[r] += p0_ + p1_;                                        \
            P[(quad * 4 + r) * 36 + col] = f2b(p0_);                    \
            P[(quad * 4 + r) * 36 + 16 + col] = f2b(p1_);               \
        }                                                               \
        p2f = *(const bf16x8*)&P[col * 36 + quad * 8];                  \
    } while (0)

#define PV_T(vs) do {                                                   \
        const u16* Vc_ = Vs[vs];                                        \
        __builtin_amdgcn_s_setprio(1);                                  \
        _Pragma("unroll")                                               \
        for (int cf = 0; cf < 16; ++cf) {                               \
            bf16x8 bv_ = *(const bf16x8*)&Vc_[(cf * 16 + col) * 32 + quad * 8]; \
            h1[cf] = MFMA16(p1f, bv_, h1[cf]);                          \
            h12[cf] = MFMA16(p2f, bv_, h12[cf]);                        \
        }                                                               \
        __builtin_amdgcn_s_setprio(0);                                  \
    } while (0)

    f32x4 s1v[2], s2v[2];

    // ---- prologue ----
    STAGE(0, 0, 0);
    __syncthreads();             // tile 0 ready
    STAGE(1, 1, 1);
    QK_T(0);                     // S(0)
    __syncthreads();             // tile 1 ready; all waves past K(0)/V-slot use

    // ---- pipelined main loop: body j computes SM(j-1), QK(j), PV(j-1) ----
    for (int j = 1; j < 32; ++j) {
        if (j < 31) STAGE(j + 1, (j + 1) & 1, (j + 1) % 3);
        bf16x8 p1f, p2f;
        SM_T();                  // softmax of S(j-1) -> p1f,p2f (then S regs free)
        QK_T(j & 1);             // S(j), overlaps SM VALU / P round-trip
        PV_T((j - 1) % 3);       // PV of tile j-1
        __syncthreads();         // tile j+1 DMA done; all waves done body j
    }

    // ---- epilogue: tile 31 ----
    {
        bf16x8 p1f, p2f;
        SM_T();
        PV_T(1);                 // 31 % 3 == 1
    }

    // ---- finalize: reduce l across the 16 col-lanes of each quad-row ----
    float inv1[4], inv2[4];
#pragma unroll
    for (int r = 0; r < 4; ++r) {
        float s = l1p[r];
        s += __shfl_xor(s, 1); s += __shfl_xor(s, 2);
        s += __shfl_xor(s, 4); s += __shfl_xor(s, 8);
        inv1[r] = 1.f / s;
        float s2x = l2p[r];
        s2x += __shfl_xor(s2x, 1); s2x += __shfl_xor(s2x, 2);
        s2x += __shfl_xor(s2x, 4); s2x += __shfl_xor(s2x, 8);
        inv2[r] = 1.f / s2x;
    }
#pragma unroll
    for (int cf = 0; cf < 16; ++cf)
#pragma unroll
        for (int r = 0; r < 4; ++r) {
            size_t addr = (size_t)(i0 + quad * 4 + r) * 256 + cf * 16 + col;
            H1T[addr] = f2b(h1[cf][r] * inv1[r]);
            H12T[addr] = f2b(h12[cf][r] * inv2[r]);
        }
#undef STAGE
#undef QK_T
#undef SM_T
#undef PV_T
}

// ---------------------------------------------------------------------------
// kfinal: out[br][b][o][n] = x1 + clamp(bias[o] + sum_c W[o][c] HT[b][n][c])
// 1-D grid 1024, XCD-clustered, block 256, fp32 output.
// ---------------------------------------------------------------------------
__global__ __launch_bounds__(256) void kfinal(
    const float* __restrict__ x1,
    const float* __restrict__ Wps, const float* __restrict__ bps,
    const float* __restrict__ Wpc, const float* __restrict__ bpc,
    const u16* __restrict__ ws, float* __restrict__ out)
{
    int blk = blockIdx.x;
    int xcd = blk & 7, jj = blk >> 3;        // jj 0..127
    int b = ((jj >> 5) << 3) + xcd;
    int rest = jj & 31;
    int br = rest >> 4, id = rest & 15;
    int mt = id >> 3, nt = id & 7;
    const u16* H = ws + (br ? OFF_H12T : OFF_H1T) + (size_t)b * NC;
    const float* W = br ? Wpc : Wps;
    const float* bb = br ? bpc : bps;
    const float* X = x1 + (size_t)b * NC;
    float* C = out + (size_t)br * REG + (size_t)b * NC;
    gemm_core(W, 1, H, 0, mt * 128, nt * 128, C, 1024, 1, bb, 1, X, 1);
}

// ---------------------------------------------------------------------------
extern "C" void kernel_launch(void* const* d_in, const int* in_sizes, int n_in,
                              void* d_out, int out_size, void* d_ws, size_t ws_size,
                              hipStream_t stream)
{
    float* out = (float*)d_out;
    u16* ws = (u16*)d_ws;

    if (ws_size < WS_NEED_BYTES) { ksig<<<1, 64, 0, stream>>>(out, 1.0e7f); return; }
    if (n_in != 12 || in_sizes[0] != 8388608 || in_sizes[1] != 8388608 ||
        in_sizes[2] != 65536 || in_sizes[3] != 256 || out_size != 16777216) {
        ksig<<<1, 64, 0, stream>>>(out, 5.0e6f); return;
    }

    const float* x1  = (const float*)d_in[0];
    const float* x2  = (const float*)d_in[1];
    const float* Wq  = (const float*)d_in[2];
    const float* bq  = (const float*)d_in[3];
    const float* Wk  = (const float*)d_in[4];
    const float* bk  = (const float*)d_in[5];
    const float* Wv  = (const float*)d_in[6];
    const float* bv  = (const float*)d_in[7];
    const float* Wps = (const float*)d_in[8];
    const float* bps = (const float*)d_in[9];
    const float* Wpc = (const float*)d_in[10];
    const float* bpc = (const float*)d_in[11];

    ktrans<<<dim3(16, 4, 64), 256, 0, stream>>>(x1, x2, ws);
    kproj<<<2560, 256, 0, stream>>>(Wq, bq, Wk, bk, Wv, bv, ws);
    kattn<<<256, 512, 0, stream>>>(ws);
    kfinal<<<1024, 256, 0, stream>>>(x1, Wps, bps, Wpc, bpc, ws, out);
}

// Round 3
// 342.868 us; speedup vs baseline: 1.1030x; 1.1030x over previous
//
#include <hip/hip_runtime.h>

// ---------------------------------------------------------------------------
// SpatialSelfCrossAttention  (B=32, C=256, H=W=32, N=1024)
// I/O fp32, internal bf16 MFMA (fp32 accum).
//
// Round-8 changes:
//  * kattn reverted to the verified round-6 version (118 us): async DMA
//    staging, K dbuf + swizzle, V dbuf linear, 1 barrier/iter. The r7
//    software pipeline doubled HBM traffic (spill/eviction churn) - dropped.
//  * NEW kprep: converts the 5 weight matrices fp32->bf16 ONCE into a
//    __device__ static array (g_wb, 640 KB). Removes the per-block
//    per-K-step f2b conversion loops from gemm_core.
//  * gemm_core is now pure-bf16: staging = 4 uint4 copies/thread/K-step.
// ---------------------------------------------------------------------------

typedef unsigned short u16;
typedef __attribute__((ext_vector_type(8))) short bf16x8;
typedef __attribute__((ext_vector_type(4))) float f32x4;

#define MFMA16(a, b, c) __builtin_amdgcn_mfma_f32_16x16x32_bf16((a), (b), (c), 0, 0, 0)

#define NC 262144ull            // 1024*256
#define REG 8388608ull          // 32*NC
#define OFF_X1T  0ull
#define OFF_X2T  (REG)
#define OFF_Q1T  (2ull*REG)
#define OFF_K1T  (3ull*REG)
#define OFF_Q2T  (4ull*REG)
#define OFF_K2T  (5ull*REG)
#define OFF_V    (6ull*REG)
#define OFF_H1T  OFF_X1T
#define OFF_H12T OFF_X2T
#define WS_NEED_BYTES (7ull*REG*2)

// bf16 weights: 0 Wq, 1 Wk, 2 Wv, 3 Wps, 4 Wpc  (converted once by kprep)
__device__ __align__(16) u16 g_wb[5][65536];

__device__ __forceinline__ float b2f(u16 u) {
    union { unsigned int i; float f; } v; v.i = ((unsigned int)u) << 16; return v.f;
}
__device__ __forceinline__ u16 f2b(float f) {
    union { float f; unsigned int i; } v; v.f = f;
    unsigned int r = (v.i + 0x7FFFu + ((v.i >> 16) & 1u)) >> 16;
    return (u16)r;
}

// async global->LDS DMA, 16 B per lane. lptr must be wave-uniform; HW adds
// lane*16. gptr is per-lane.
__device__ __forceinline__ void gload16(const u16* g, u16* l) {
    __builtin_amdgcn_global_load_lds(
        (const __attribute__((address_space(1))) void*)g,
        (__attribute__((address_space(3))) void*)l,
        16, 0, 0);
}

__global__ void ksig(float* out, float val) {
    if (threadIdx.x == 0 && blockIdx.x == 0) out[0] = val;
}

// ---------------------------------------------------------------------------
// kprep: 5x 256x256 fp32 weights -> bf16 g_wb. grid 320, block 256.
// ---------------------------------------------------------------------------
__global__ __launch_bounds__(256) void kprep(
    const float* __restrict__ Wq, const float* __restrict__ Wk,
    const float* __restrict__ Wv, const float* __restrict__ Wps,
    const float* __restrict__ Wpc)
{
    int blk = blockIdx.x;
    int w = blk >> 6, j = blk & 63;
    const float* src = (w == 0) ? Wq : (w == 1) ? Wk : (w == 2) ? Wv : (w == 3) ? Wps : Wpc;
    int idx = j * 1024 + threadIdx.x * 4;
    float4 v = *(const float4*)(src + idx);
    ushort4 o;
    o.x = f2b(v.x); o.y = f2b(v.y); o.z = f2b(v.z); o.w = f2b(v.w);
    *(ushort4*)&g_wb[w][idx] = o;
}

// ---------------------------------------------------------------------------
// ktrans: X[b][c][n] fp32 -> XT[b][n][c] bf16. grid (16,4,64), block 256.
// ---------------------------------------------------------------------------
__global__ __launch_bounds__(256) void ktrans(
    const float* __restrict__ x1, const float* __restrict__ x2, u16* __restrict__ ws)
{
    int nt = blockIdx.x, ct = blockIdx.y, bz = blockIdx.z;
    int b = bz >> 1, which = bz & 1;
    const float* X = (which ? x2 : x1) + (size_t)b * NC;
    u16* XT = ws + (which ? OFF_X2T : OFF_X1T) + (size_t)b * NC;
    int c0 = ct * 64, n0 = nt * 64;

    __shared__ __align__(16) u16 tile[64][68];
    int t = threadIdx.x;
    int tn = t & 15, tc = t >> 4;
#pragma unroll
    for (int j = 0; j < 4; ++j) {
        float4 v = *(const float4*)(X + (size_t)(c0 + 4 * tc + j) * 1024 + n0 + 4 * tn);
        u16* d = &tile[4 * tc + j][4 * tn];
        d[0] = f2b(v.x); d[1] = f2b(v.y); d[2] = f2b(v.z); d[3] = f2b(v.w);
    }
    __syncthreads();
    int tcB = t & 15, tnB = t >> 4;
#pragma unroll
    for (int i = 0; i < 4; ++i) {
        ushort4 o;
        o.x = tile[4 * tcB + 0][4 * tnB + i];
        o.y = tile[4 * tcB + 1][4 * tnB + i];
        o.z = tile[4 * tcB + 2][4 * tnB + i];
        o.w = tile[4 * tcB + 3][4 * tnB + i];
        *(ushort4*)(XT + (size_t)(n0 + 4 * tnB + i) * 256 + c0 + 4 * tcB) = o;
    }
}

// ---------------------------------------------------------------------------
// gemm_core (pure bf16): C[128x128] = A[m][k=256] * B[n][k=256]^T
// (+bias, +clamped-h, +fp32 residual). Same tiling as the verified r3 core;
// fp32 staging paths removed (weights pre-converted by kprep).
// ---------------------------------------------------------------------------
__device__ __forceinline__ void gemm_core(
    const u16* __restrict__ A, const u16* __restrict__ B,
    int m0, int n0,
    void* __restrict__ C, int ldc, int cF32,
    const float* __restrict__ bias, int biasPerRow,
    const float* __restrict__ addSrc, int clampH)
{
    __shared__ __align__(16) u16 As[128 * 40];
    __shared__ __align__(16) u16 Bs[128 * 40];
    int t = threadIdx.x;
    int lane = t & 63, wave = t >> 6;
    int wm = wave >> 1, wn = wave & 1;
    int col = lane & 15, quad = lane >> 4;

    f32x4 acc[4][4];
#pragma unroll
    for (int i = 0; i < 4; ++i)
#pragma unroll
        for (int j = 0; j < 4; ++j) acc[i][j] = f32x4{0.f, 0.f, 0.f, 0.f};

    int r1 = t >> 2, c1 = t & 3;
    int r2 = r1 + 64;

    for (int kt = 0; kt < 8; ++kt) {
        int k0 = kt * 32;
        __syncthreads();
        *(uint4*)&As[r1 * 40 + c1 * 8] = *(const uint4*)(A + (size_t)(m0 + r1) * 256 + k0 + c1 * 8);
        *(uint4*)&As[r2 * 40 + c1 * 8] = *(const uint4*)(A + (size_t)(m0 + r2) * 256 + k0 + c1 * 8);
        *(uint4*)&Bs[r1 * 40 + c1 * 8] = *(const uint4*)(B + (size_t)(n0 + r1) * 256 + k0 + c1 * 8);
        *(uint4*)&Bs[r2 * 40 + c1 * 8] = *(const uint4*)(B + (size_t)(n0 + r2) * 256 + k0 + c1 * 8);
        __syncthreads();

        bf16x8 af[4], bf[4];
#pragma unroll
        for (int mf = 0; mf < 4; ++mf)
            af[mf] = *(const bf16x8*)&As[(wm * 64 + mf * 16 + col) * 40 + quad * 8];
#pragma unroll
        for (int nf = 0; nf < 4; ++nf)
            bf[nf] = *(const bf16x8*)&Bs[(wn * 64 + nf * 16 + col) * 40 + quad * 8];
#pragma unroll
        for (int mf = 0; mf < 4; ++mf)
#pragma unroll
            for (int nf = 0; nf < 4; ++nf)
                acc[mf][nf] = MFMA16(af[mf], bf[nf], acc[mf][nf]);
    }

#pragma unroll
    for (int mf = 0; mf < 4; ++mf)
#pragma unroll
        for (int nf = 0; nf < 4; ++nf) {
            int gm = m0 + wm * 64 + mf * 16 + quad * 4;
            int gn = n0 + wn * 64 + nf * 16 + col;
            float bcol = biasPerRow ? 0.f : bias[gn];
#pragma unroll
            for (int r = 0; r < 4; ++r) {
                int row = gm + r;
                float hv = acc[mf][nf][r] + (biasPerRow ? bias[row] : bcol);
                if (clampH) hv = fminf(fmaxf(hv, -0.05f), 0.05f);
                size_t ci = (size_t)row * ldc + gn;
                float v = hv + (addSrc ? addSrc[ci] : 0.f);
                if (cF32) ((float*)C)[ci] = v;
                else ((u16*)C)[ci] = f2b(v);
            }
        }
}

// ---------------------------------------------------------------------------
// kproj: 5 projections per batch. 1-D grid 2560, XCD-clustered, block 256.
//  id<64:  (id>>4): 0 Q1T, 1 K1T, 2 Q2T, 3 K2T -> [1024 n][256 o] bf16
//  id>=64: V[256 o][1024 n] bf16
// ---------------------------------------------------------------------------
__global__ __launch_bounds__(256) void kproj(
    const float* __restrict__ bq, const float* __restrict__ bk,
    const float* __restrict__ bv, u16* __restrict__ ws)
{
    int blk = blockIdx.x;
    int xcd = blk & 7, jj = blk >> 3;       // jj 0..319
    int bg = jj / 80, id = jj % 80;
    int b = bg * 8 + xcd;                   // batches serialize per XCD
    const u16* X1T = ws + OFF_X1T + (size_t)b * NC;
    const u16* X2T = ws + OFF_X2T + (size_t)b * NC;
    if (id < 64) {
        int out = id >> 4, tt = id & 15, mt = tt >> 1, nt = tt & 1;
        const u16* A = (out < 2) ? X1T : X2T;
        const u16* W = (out & 1) ? &g_wb[1][0] : &g_wb[0][0];
        const float* bb = (out & 1) ? bk : bq;
        size_t off = (out == 0) ? OFF_Q1T : (out == 1) ? OFF_K1T : (out == 2) ? OFF_Q2T : OFF_K2T;
        u16* C = ws + off + (size_t)b * NC;
        gemm_core(A, W, mt * 128, nt * 128, C, 256, 0, bb, 0, nullptr, 0);
    } else {
        int tt = id - 64, mt = tt >> 3, nt = tt & 7;
        u16* C = ws + OFF_V + (size_t)b * NC;
        gemm_core(&g_wb[2][0], X1T, mt * 128, nt * 128, C, 1024, 0, bv, 1, nullptr, 0);
    }
}

// ---------------------------------------------------------------------------
// kattn (verified round-6 version, 118 us): grid 256 (XCD-clustered),
// block 512 = 8 waves x 16 queries. Double-buffered async staging via
// global_load_lds; ONE barrier per iter.
// LDS: K1s 32K + K2s 32K + Vs 32K + Ps 9K = 105 KB (1 block/CU).
//
// K tile layout (per buffer): [32 key-rows][256 ch] u16, stored byte offset
// within a row XOR'd with ((row&7)<<4). Source addresses pre-swizzled so the
// lane-linear DMA lands data swizzled; reads apply the same XOR.
// V tile layout: [256 ch][32 keys] u16, linear (read pattern already uniform).
// ---------------------------------------------------------------------------
__global__ __launch_bounds__(512, 2) void kattn(u16* __restrict__ ws)
{
    int blk = blockIdx.x;
    int xcd = blk & 7, jj = blk >> 3;        // jj 0..31
    int b = ((jj >> 3) << 3) + xcd;          // 4 batch-groups, serialized per XCD
    int qt = jj & 7;                         // 8 q-tiles of 128 queries
    int t = threadIdx.x, lane = t & 63, wave = t >> 6;   // wave 0..7
    int col = lane & 15, quad = lane >> 4;

    const u16* Q1T = ws + OFF_Q1T + (size_t)b * NC;
    const u16* K1T = ws + OFF_K1T + (size_t)b * NC;
    const u16* Q2T = ws + OFF_Q2T + (size_t)b * NC;
    const u16* K2T = ws + OFF_K2T + (size_t)b * NC;
    const u16* V   = ws + OFF_V   + (size_t)b * NC;
    u16* H1T  = ws + OFF_H1T  + (size_t)b * NC;
    u16* H12T = ws + OFF_H12T + (size_t)b * NC;

    __shared__ __align__(16) u16 K1s[2][8192];   // [buf][32*256]
    __shared__ __align__(16) u16 K2s[2][8192];
    __shared__ __align__(16) u16 Vs[2][8192];    // [buf][256*32]
    __shared__ __align__(16) u16 Ps[8][16 * 36];

    int i0 = qt * 128 + wave * 16;

    // Q fragments in registers: A[m=col][k = f*32 + quad*8 + j]
    bf16x8 aq1[8], aq2[8];
#pragma unroll
    for (int f = 0; f < 8; ++f) {
        aq1[f] = *(const bf16x8*)(Q1T + (size_t)(i0 + col) * 256 + f * 32 + quad * 8);
        aq2[f] = *(const bf16x8*)(Q2T + (size_t)(i0 + col) * 256 + f * 32 + quad * 8);
    }

    f32x4 h1[16], h12[16];
#pragma unroll
    for (int cf = 0; cf < 16; ++cf) { h1[cf] = f32x4{0.f,0.f,0.f,0.f}; h12[cf] = f32x4{0.f,0.f,0.f,0.f}; }
    float l1p[4], l2p[4];
#pragma unroll
    for (int r = 0; r < 4; ++r) { l1p[r] = 0.f; l2p[r] = 0.f; }

    const float sc = 0.0901684400555602f;   // log2(e)/16
    const float SH = 5.770780163555851f;    // 4*log2(e): fixed shift, overflow-safe

    // ---- staging geometry (loop-invariant per thread) ----
    int kr_ = t >> 5;                        // key row, shot 0
    int kwb = (t & 31) << 4;                 // stored byte offset
    int kwl = kwb ^ ((kr_ & 7) << 4);        // logical (source) byte offset
    const u16* k1src = K1T + (size_t)kr_ * 256 + (kwl >> 1);
    const u16* k2src = K2T + (size_t)kr_ * 256 + (kwl >> 1);
    int vrow = t >> 2;                       // channel, shot 0
    int vo = (t & 3) << 3;
    const u16* vsrc = V + (size_t)vrow * 1024 + vo;
    int ldsw = wave * 512;                   // wave-uniform LDS base (u16)

    // ---- prologue: async-stage tile 0 into buffer 0 ----
    gload16(k1src,          &K1s[0][ldsw]);
    gload16(k1src + 4096,   &K1s[0][ldsw + 4096]);
    gload16(k2src,          &K2s[0][ldsw]);
    gload16(k2src + 4096,   &K2s[0][ldsw + 4096]);
    gload16(vsrc,           &Vs[0][ldsw]);
    gload16(vsrc + 131072,  &Vs[0][ldsw + 4096]);

    u16* P = Ps[wave];
    int swz = (col & 7) << 3;                // read-side XOR, u16 units

    for (int it = 0; it < 32; ++it) {
        int cur = it & 1;
        __syncthreads();   // drains vmcnt (DMA of tile `it` done) + barrier

        // ---- async-stage tile it+1 into the other buffer ----
        if (it < 31) {
            int nxt = cur ^ 1;
            const u16* s1 = k1src + (size_t)(it + 1) * 8192;   // +32 key rows
            const u16* s2 = k2src + (size_t)(it + 1) * 8192;
            const u16* sv = vsrc + (size_t)(it + 1) * 32;      // +32 keys
            gload16(s1,          &K1s[nxt][ldsw]);
            gload16(s1 + 4096,   &K1s[nxt][ldsw + 4096]);
            gload16(s2,          &K2s[nxt][ldsw]);
            gload16(s2 + 4096,   &K2s[nxt][ldsw + 4096]);
            gload16(sv,          &Vs[nxt][ldsw]);
            gload16(sv + 131072, &Vs[nxt][ldsw + 4096]);
        }

        const u16* K1c = K1s[cur];
        const u16* K2c = K2s[cur];
        const u16* Vc  = Vs[cur];

        // ---- QK: S1, S2 : D[row=quad*4+r (query)][col (key)] ----
        f32x4 s1v[2], s2v[2];
        s1v[0] = s1v[1] = s2v[0] = s2v[1] = f32x4{0.f,0.f,0.f,0.f};
        __builtin_amdgcn_s_setprio(1);
#pragma unroll
        for (int nf = 0; nf < 2; ++nf) {
            int krow = nf * 16 + col;
#pragma unroll
            for (int f = 0; f < 8; ++f) {
                int wb = (f * 32 + quad * 8) ^ swz;            // swizzled u16 off
                bf16x8 bk1 = *(const bf16x8*)&K1c[krow * 256 + wb];
                s1v[nf] = MFMA16(aq1[f], bk1, s1v[nf]);
                bf16x8 bk2 = *(const bf16x8*)&K2c[krow * 256 + wb];
                s2v[nf] = MFMA16(aq2[f], bk2, s2v[nf]);
            }
        }
        __builtin_amdgcn_s_setprio(0);

        // ---- fixed-shift softmax, branch 1 -> P, pull frag ----
#pragma unroll
        for (int r = 0; r < 4; ++r) {
            float p0 = __builtin_amdgcn_exp2f(s1v[0][r] * sc - SH);
            float p1 = __builtin_amdgcn_exp2f(s1v[1][r] * sc - SH);
            l1p[r] += p0 + p1;
            P[(quad * 4 + r) * 36 + col] = f2b(p0);
            P[(quad * 4 + r) * 36 + 16 + col] = f2b(p1);
        }
        bf16x8 p1f = *(const bf16x8*)&P[col * 36 + quad * 8];

        // ---- branch 12 (reuses P region; within-wave DS is in-order) ----
#pragma unroll
        for (int r = 0; r < 4; ++r) {
            float s0 = s1v[0][r] + s2v[0][r];
            float s1x = s1v[1][r] + s2v[1][r];
            float p0 = __builtin_amdgcn_exp2f(s0 * sc - SH);
            float p1 = __builtin_amdgcn_exp2f(s1x * sc - SH);
            l2p[r] += p0 + p1;
            P[(quad * 4 + r) * 36 + col] = f2b(p0);
            P[(quad * 4 + r) * 36 + 16 + col] = f2b(p1);
        }
        bf16x8 p2f = *(const bf16x8*)&P[col * 36 + quad * 8];

        // ---- PV: shared V-frag for both branches ----
        __builtin_amdgcn_s_setprio(1);
#pragma unroll
        for (int cf = 0; cf < 16; ++cf) {
            bf16x8 bv = *(const bf16x8*)&Vc[(cf * 16 + col) * 32 + quad * 8];
            h1[cf] = MFMA16(p1f, bv, h1[cf]);
            h12[cf] = MFMA16(p2f, bv, h12[cf]);
        }
        __builtin_amdgcn_s_setprio(0);
    }

    // ---- finalize: reduce l across the 16 col-lanes of each quad-row ----
    float inv1[4], inv2[4];
#pragma unroll
    for (int r = 0; r < 4; ++r) {
        float s = l1p[r];
        s += __shfl_xor(s, 1); s += __shfl_xor(s, 2);
        s += __shfl_xor(s, 4); s += __shfl_xor(s, 8);
        inv1[r] = 1.f / s;
        float s2x = l2p[r];
        s2x += __shfl_xor(s2x, 1); s2x += __shfl_xor(s2x, 2);
        s2x += __shfl_xor(s2x, 4); s2x += __shfl_xor(s2x, 8);
        inv2[r] = 1.f / s2x;
    }
#pragma unroll
    for (int cf = 0; cf < 16; ++cf)
#pragma unroll
        for (int r = 0; r < 4; ++r) {
            size_t addr = (size_t)(i0 + quad * 4 + r) * 256 + cf * 16 + col;
            H1T[addr] = f2b(h1[cf][r] * inv1[r]);
            H12T[addr] = f2b(h12[cf][r] * inv2[r]);
        }
}

// ---------------------------------------------------------------------------
// kfinal: out[br][b][o][n] = x1 + clamp(bias[o] + sum_c W[o][c] HT[b][n][c])
// 1-D grid 1024, XCD-clustered, block 256, fp32 output.
// ---------------------------------------------------------------------------
__global__ __launch_bounds__(256) void kfinal(
    const float* __restrict__ x1,
    const float* __restrict__ bps, const float* __restrict__ bpc,
    const u16* __restrict__ ws, float* __restrict__ out)
{
    int blk = blockIdx.x;
    int xcd = blk & 7, jj = blk >> 3;        // jj 0..127
    int b = ((jj >> 5) << 3) + xcd;
    int rest = jj & 31;
    int br = rest >> 4, id = rest & 15;
    int mt = id >> 3, nt = id & 7;
    const u16* H = ws + (br ? OFF_H12T : OFF_H1T) + (size_t)b * NC;
    const u16* W = br ? &g_wb[4][0] : &g_wb[3][0];
    const float* bb = br ? bpc : bps;
    const float* X = x1 + (size_t)b * NC;
    float* C = out + (size_t)br * REG + (size_t)b * NC;
    gemm_core(W, H, mt * 128, nt * 128, C, 1024, 1, bb, 1, X, 1);
}

// ---------------------------------------------------------------------------
extern "C" void kernel_launch(void* const* d_in, const int* in_sizes, int n_in,
                              void* d_out, int out_size, void* d_ws, size_t ws_size,
                              hipStream_t stream)
{
    float* out = (float*)d_out;
    u16* ws = (u16*)d_ws;

    if (ws_size < WS_NEED_BYTES) { ksig<<<1, 64, 0, stream>>>(out, 1.0e7f); return; }
    if (n_in != 12 || in_sizes[0] != 8388608 || in_sizes[1] != 8388608 ||
        in_sizes[2] != 65536 || in_sizes[3] != 256 || out_size != 16777216) {
        ksig<<<1, 64, 0, stream>>>(out, 5.0e6f); return;
    }

    const float* x1  = (const float*)d_in[0];
    const float* x2  = (const float*)d_in[1];
    const float* Wq  = (const float*)d_in[2];
    const float* bq  = (const float*)d_in[3];
    const float* Wk  = (const float*)d_in[4];
    const float* bk  = (const float*)d_in[5];
    const float* Wv  = (const float*)d_in[6];
    const float* bv  = (const float*)d_in[7];
    const float* Wps = (const float*)d_in[8];
    const float* bps = (const float*)d_in[9];
    const float* Wpc = (const float*)d_in[10];
    const float* bpc = (const float*)d_in[11];

    kprep<<<320, 256, 0, stream>>>(Wq, Wk, Wv, Wps, Wpc);
    ktrans<<<dim3(16, 4, 64), 256, 0, stream>>>(x1, x2, ws);
    kproj<<<2560, 256, 0, stream>>>(bq, bk, bv, ws);
    kattn<<<256, 512, 0, stream>>>(ws);
    kfinal<<<1024, 256, 0, stream>>>(x1, bps, bpc, ws, out);
}

// Round 4
// 328.744 us; speedup vs baseline: 1.1504x; 1.0430x over previous
//
#include <hip/hip_runtime.h>

// ---------------------------------------------------------------------------
// SpatialSelfCrossAttention  (B=32, C=256, H=W=32, N=1024)
// I/O fp32, internal bf16 MFMA (fp32 accum).
//
// Round-9 changes:
//  * gemm_core v2: async global_load_lds staging (the verified kattn r6
//    pattern), double-buffered BK=32 K-slabs, ONE barrier per K-step
//    (was: 2 barriers + VGPR round-trip staging). LDS 32 KB/block.
//    Chunk-XOR swizzle (stored 16B chunk = logical ^ ((row>>1)&3)),
//    pre-swizzled global source, same XOR on frag reads -> 2-way (free).
//  * kattn / ktrans / kprep unchanged (kattn = verified 117 us version).
// ---------------------------------------------------------------------------

typedef unsigned short u16;
typedef __attribute__((ext_vector_type(8))) short bf16x8;
typedef __attribute__((ext_vector_type(4))) float f32x4;

#define MFMA16(a, b, c) __builtin_amdgcn_mfma_f32_16x16x32_bf16((a), (b), (c), 0, 0, 0)

#define NC 262144ull            // 1024*256
#define REG 8388608ull          // 32*NC
#define OFF_X1T  0ull
#define OFF_X2T  (REG)
#define OFF_Q1T  (2ull*REG)
#define OFF_K1T  (3ull*REG)
#define OFF_Q2T  (4ull*REG)
#define OFF_K2T  (5ull*REG)
#define OFF_V    (6ull*REG)
#define OFF_H1T  OFF_X1T
#define OFF_H12T OFF_X2T
#define WS_NEED_BYTES (7ull*REG*2)

// bf16 weights: 0 Wq, 1 Wk, 2 Wv, 3 Wps, 4 Wpc  (converted once by kprep)
__device__ __align__(16) u16 g_wb[5][65536];

__device__ __forceinline__ float b2f(u16 u) {
    union { unsigned int i; float f; } v; v.i = ((unsigned int)u) << 16; return v.f;
}
__device__ __forceinline__ u16 f2b(float f) {
    union { float f; unsigned int i; } v; v.f = f;
    unsigned int r = (v.i + 0x7FFFu + ((v.i >> 16) & 1u)) >> 16;
    return (u16)r;
}

// async global->LDS DMA, 16 B per lane. lptr must be wave-uniform; HW adds
// lane*16. gptr is per-lane.
__device__ __forceinline__ void gload16(const u16* g, u16* l) {
    __builtin_amdgcn_global_load_lds(
        (const __attribute__((address_space(1))) void*)g,
        (__attribute__((address_space(3))) void*)l,
        16, 0, 0);
}

__global__ void ksig(float* out, float val) {
    if (threadIdx.x == 0 && blockIdx.x == 0) out[0] = val;
}

// ---------------------------------------------------------------------------
// kprep: 5x 256x256 fp32 weights -> bf16 g_wb. grid 320, block 256.
// ---------------------------------------------------------------------------
__global__ __launch_bounds__(256) void kprep(
    const float* __restrict__ Wq, const float* __restrict__ Wk,
    const float* __restrict__ Wv, const float* __restrict__ Wps,
    const float* __restrict__ Wpc)
{
    int blk = blockIdx.x;
    int w = blk >> 6, j = blk & 63;
    const float* src = (w == 0) ? Wq : (w == 1) ? Wk : (w == 2) ? Wv : (w == 3) ? Wps : Wpc;
    int idx = j * 1024 + threadIdx.x * 4;
    float4 v = *(const float4*)(src + idx);
    ushort4 o;
    o.x = f2b(v.x); o.y = f2b(v.y); o.z = f2b(v.z); o.w = f2b(v.w);
    *(ushort4*)&g_wb[w][idx] = o;
}

// ---------------------------------------------------------------------------
// ktrans: X[b][c][n] fp32 -> XT[b][n][c] bf16. grid (16,4,64), block 256.
// ---------------------------------------------------------------------------
__global__ __launch_bounds__(256) void ktrans(
    const float* __restrict__ x1, const float* __restrict__ x2, u16* __restrict__ ws)
{
    int nt = blockIdx.x, ct = blockIdx.y, bz = blockIdx.z;
    int b = bz >> 1, which = bz & 1;
    const float* X = (which ? x2 : x1) + (size_t)b * NC;
    u16* XT = ws + (which ? OFF_X2T : OFF_X1T) + (size_t)b * NC;
    int c0 = ct * 64, n0 = nt * 64;

    __shared__ __align__(16) u16 tile[64][68];
    int t = threadIdx.x;
    int tn = t & 15, tc = t >> 4;
#pragma unroll
    for (int j = 0; j < 4; ++j) {
        float4 v = *(const float4*)(X + (size_t)(c0 + 4 * tc + j) * 1024 + n0 + 4 * tn);
        u16* d = &tile[4 * tc + j][4 * tn];
        d[0] = f2b(v.x); d[1] = f2b(v.y); d[2] = f2b(v.z); d[3] = f2b(v.w);
    }
    __syncthreads();
    int tcB = t & 15, tnB = t >> 4;
#pragma unroll
    for (int i = 0; i < 4; ++i) {
        ushort4 o;
        o.x = tile[4 * tcB + 0][4 * tnB + i];
        o.y = tile[4 * tcB + 1][4 * tnB + i];
        o.z = tile[4 * tcB + 2][4 * tnB + i];
        o.w = tile[4 * tcB + 3][4 * tnB + i];
        *(ushort4*)(XT + (size_t)(n0 + 4 * tnB + i) * 256 + c0 + 4 * tcB) = o;
    }
}

// ---------------------------------------------------------------------------
// gemm_core v2 (pure bf16, async DMA staging): C[128x128] = A[m][256] *
// B[n][256]^T (+bias, +clamped-h, +fp32 residual).
//
// LDS slab layout per buffer: [128 rows][32 u16], 16B chunk c of row r holds
// logical chunk c ^ ((r>>1)&3) (source pre-swizzled; reads apply same XOR).
// Frag-read bank pattern: 2-way (free). Staging global pattern byte-identical
// to v1 (rows t>>2, chunk t&3).
// ---------------------------------------------------------------------------
__device__ __forceinline__ void gemm_core(
    const u16* __restrict__ A, const u16* __restrict__ B,
    int m0, int n0,
    void* __restrict__ C, int ldc, int cF32,
    const float* __restrict__ bias, int biasPerRow,
    const float* __restrict__ addSrc, int clampH)
{
    __shared__ __align__(16) u16 As[2][4096];   // [buf][128*32]
    __shared__ __align__(16) u16 Bs[2][4096];
    int t = threadIdx.x;
    int lane = t & 63, wave = t >> 6;
    int wm = wave >> 1, wn = wave & 1;
    int col = lane & 15, quad = lane >> 4;

    f32x4 acc[4][4];
#pragma unroll
    for (int i = 0; i < 4; ++i)
#pragma unroll
        for (int j = 0; j < 4; ++j) acc[i][j] = f32x4{0.f, 0.f, 0.f, 0.f};

    // staging geometry: thread t covers row rA = t>>2 (and +64), stored
    // chunk t&3 which holds logical chunk (t&3)^((t>>3)&3).
    int rA = t >> 2;
    int lA = (((t & 3) ^ ((t >> 3) & 3)) << 3);        // u16 offset in row
    const u16* aB = A + (size_t)(m0 + rA) * 256 + lA;
    const u16* bB = B + (size_t)(n0 + rA) * 256 + lA;
    int ldsw = wave * 512;                              // u16; +2048 for rows 64..127

    // read-side chunk XOR (frag-invariant): quad ^ ((col>>1)&3)
    int rchunk = ((quad ^ ((col >> 1) & 3)) << 3);

    // prologue: stage kt=0 into buf 0
    gload16(aB,          &As[0][ldsw]);
    gload16(aB + 16384,  &As[0][ldsw + 2048]);
    gload16(bB,          &Bs[0][ldsw]);
    gload16(bB + 16384,  &Bs[0][ldsw + 2048]);

    for (int kt = 0; kt < 8; ++kt) {
        int cur = kt & 1;
        __syncthreads();          // vmcnt drain: slab kt resident; buf[cur^1] free
        if (kt < 7) {
            int off = (kt + 1) * 32;
            gload16(aB + off,          &As[cur ^ 1][ldsw]);
            gload16(aB + off + 16384,  &As[cur ^ 1][ldsw + 2048]);
            gload16(bB + off,          &Bs[cur ^ 1][ldsw]);
            gload16(bB + off + 16384,  &Bs[cur ^ 1][ldsw + 2048]);
        }

        bf16x8 af[4], bf[4];
#pragma unroll
        for (int mf = 0; mf < 4; ++mf)
            af[mf] = *(const bf16x8*)&As[cur][(wm * 64 + mf * 16 + col) * 32 + rchunk];
#pragma unroll
        for (int nf = 0; nf < 4; ++nf)
            bf[nf] = *(const bf16x8*)&Bs[cur][(wn * 64 + nf * 16 + col) * 32 + rchunk];
        __builtin_amdgcn_s_setprio(1);
#pragma unroll
        for (int mf = 0; mf < 4; ++mf)
#pragma unroll
            for (int nf = 0; nf < 4; ++nf)
                acc[mf][nf] = MFMA16(af[mf], bf[nf], acc[mf][nf]);
        __builtin_amdgcn_s_setprio(0);
    }

#pragma unroll
    for (int mf = 0; mf < 4; ++mf)
#pragma unroll
        for (int nf = 0; nf < 4; ++nf) {
            int gm = m0 + wm * 64 + mf * 16 + quad * 4;
            int gn = n0 + wn * 64 + nf * 16 + col;
            float bcol = biasPerRow ? 0.f : bias[gn];
#pragma unroll
            for (int r = 0; r < 4; ++r) {
                int row = gm + r;
                float hv = acc[mf][nf][r] + (biasPerRow ? bias[row] : bcol);
                if (clampH) hv = fminf(fmaxf(hv, -0.05f), 0.05f);
                size_t ci = (size_t)row * ldc + gn;
                float v = hv + (addSrc ? addSrc[ci] : 0.f);
                if (cF32) ((float*)C)[ci] = v;
                else ((u16*)C)[ci] = f2b(v);
            }
        }
}

// ---------------------------------------------------------------------------
// kproj: 5 projections per batch. 1-D grid 2560, XCD-clustered, block 256.
//  id<64:  (id>>4): 0 Q1T, 1 K1T, 2 Q2T, 3 K2T -> [1024 n][256 o] bf16
//  id>=64: V[256 o][1024 n] bf16
// ---------------------------------------------------------------------------
__global__ __launch_bounds__(256) void kproj(
    const float* __restrict__ bq, const float* __restrict__ bk,
    const float* __restrict__ bv, u16* __restrict__ ws)
{
    int blk = blockIdx.x;
    int xcd = blk & 7, jj = blk >> 3;       // jj 0..319
    int bg = jj / 80, id = jj % 80;
    int b = bg * 8 + xcd;                   // batches serialize per XCD
    const u16* X1T = ws + OFF_X1T + (size_t)b * NC;
    const u16* X2T = ws + OFF_X2T + (size_t)b * NC;
    if (id < 64) {
        int out = id >> 4, tt = id & 15, mt = tt >> 1, nt = tt & 1;
        const u16* A = (out < 2) ? X1T : X2T;
        const u16* W = (out & 1) ? &g_wb[1][0] : &g_wb[0][0];
        const float* bb = (out & 1) ? bk : bq;
        size_t off = (out == 0) ? OFF_Q1T : (out == 1) ? OFF_K1T : (out == 2) ? OFF_Q2T : OFF_K2T;
        u16* C = ws + off + (size_t)b * NC;
        gemm_core(A, W, mt * 128, nt * 128, C, 256, 0, bb, 0, nullptr, 0);
    } else {
        int tt = id - 64, mt = tt >> 3, nt = tt & 7;
        u16* C = ws + OFF_V + (size_t)b * NC;
        gemm_core(&g_wb[2][0], X1T, mt * 128, nt * 128, C, 1024, 0, bv, 1, nullptr, 0);
    }
}

// ---------------------------------------------------------------------------
// kattn (verified round-6 version, 117 us): grid 256 (XCD-clustered),
// block 512 = 8 waves x 16 queries. Double-buffered async staging via
// global_load_lds; ONE barrier per iter.
// LDS: K1s 32K + K2s 32K + Vs 32K + Ps 9K = 105 KB (1 block/CU).
// ---------------------------------------------------------------------------
__global__ __launch_bounds__(512, 2) void kattn(u16* __restrict__ ws)
{
    int blk = blockIdx.x;
    int xcd = blk & 7, jj = blk >> 3;        // jj 0..31
    int b = ((jj >> 3) << 3) + xcd;          // 4 batch-groups, serialized per XCD
    int qt = jj & 7;                         // 8 q-tiles of 128 queries
    int t = threadIdx.x, lane = t & 63, wave = t >> 6;   // wave 0..7
    int col = lane & 15, quad = lane >> 4;

    const u16* Q1T = ws + OFF_Q1T + (size_t)b * NC;
    const u16* K1T = ws + OFF_K1T + (size_t)b * NC;
    const u16* Q2T = ws + OFF_Q2T + (size_t)b * NC;
    const u16* K2T = ws + OFF_K2T + (size_t)b * NC;
    const u16* V   = ws + OFF_V   + (size_t)b * NC;
    u16* H1T  = ws + OFF_H1T  + (size_t)b * NC;
    u16* H12T = ws + OFF_H12T + (size_t)b * NC;

    __shared__ __align__(16) u16 K1s[2][8192];   // [buf][32*256]
    __shared__ __align__(16) u16 K2s[2][8192];
    __shared__ __align__(16) u16 Vs[2][8192];    // [buf][256*32]
    __shared__ __align__(16) u16 Ps[8][16 * 36];

    int i0 = qt * 128 + wave * 16;

    // Q fragments in registers: A[m=col][k = f*32 + quad*8 + j]
    bf16x8 aq1[8], aq2[8];
#pragma unroll
    for (int f = 0; f < 8; ++f) {
        aq1[f] = *(const bf16x8*)(Q1T + (size_t)(i0 + col) * 256 + f * 32 + quad * 8);
        aq2[f] = *(const bf16x8*)(Q2T + (size_t)(i0 + col) * 256 + f * 32 + quad * 8);
    }

    f32x4 h1[16], h12[16];
#pragma unroll
    for (int cf = 0; cf < 16; ++cf) { h1[cf] = f32x4{0.f,0.f,0.f,0.f}; h12[cf] = f32x4{0.f,0.f,0.f,0.f}; }
    float l1p[4], l2p[4];
#pragma unroll
    for (int r = 0; r < 4; ++r) { l1p[r] = 0.f; l2p[r] = 0.f; }

    const float sc = 0.0901684400555602f;   // log2(e)/16
    const float SH = 5.770780163555851f;    // 4*log2(e): fixed shift, overflow-safe

    // ---- staging geometry (loop-invariant per thread) ----
    int kr_ = t >> 5;                        // key row, shot 0
    int kwb = (t & 31) << 4;                 // stored byte offset
    int kwl = kwb ^ ((kr_ & 7) << 4);        // logical (source) byte offset
    const u16* k1src = K1T + (size_t)kr_ * 256 + (kwl >> 1);
    const u16* k2src = K2T + (size_t)kr_ * 256 + (kwl >> 1);
    int vrow = t >> 2;                       // channel, shot 0
    int vo = (t & 3) << 3;
    const u16* vsrc = V + (size_t)vrow * 1024 + vo;
    int ldsw = wave * 512;                   // wave-uniform LDS base (u16)

    // ---- prologue: async-stage tile 0 into buffer 0 ----
    gload16(k1src,          &K1s[0][ldsw]);
    gload16(k1src + 4096,   &K1s[0][ldsw + 4096]);
    gload16(k2src,          &K2s[0][ldsw]);
    gload16(k2src + 4096,   &K2s[0][ldsw + 4096]);
    gload16(vsrc,           &Vs[0][ldsw]);
    gload16(vsrc + 131072,  &Vs[0][ldsw + 4096]);

    u16* P = Ps[wave];
    int swz = (col & 7) << 3;                // read-side XOR, u16 units

    for (int it = 0; it < 32; ++it) {
        int cur = it & 1;
        __syncthreads();   // drains vmcnt (DMA of tile `it` done) + barrier

        // ---- async-stage tile it+1 into the other buffer ----
        if (it < 31) {
            int nxt = cur ^ 1;
            const u16* s1 = k1src + (size_t)(it + 1) * 8192;   // +32 key rows
            const u16* s2 = k2src + (size_t)(it + 1) * 8192;
            const u16* sv = vsrc + (size_t)(it + 1) * 32;      // +32 keys
            gload16(s1,          &K1s[nxt][ldsw]);
            gload16(s1 + 4096,   &K1s[nxt][ldsw + 4096]);
            gload16(s2,          &K2s[nxt][ldsw]);
            gload16(s2 + 4096,   &K2s[nxt][ldsw + 4096]);
            gload16(sv,          &Vs[nxt][ldsw]);
            gload16(sv + 131072, &Vs[nxt][ldsw + 4096]);
        }

        const u16* K1c = K1s[cur];
        const u16* K2c = K2s[cur];
        const u16* Vc  = Vs[cur];

        // ---- QK: S1, S2 : D[row=quad*4+r (query)][col (key)] ----
        f32x4 s1v[2], s2v[2];
        s1v[0] = s1v[1] = s2v[0] = s2v[1] = f32x4{0.f,0.f,0.f,0.f};
        __builtin_amdgcn_s_setprio(1);
#pragma unroll
        for (int nf = 0; nf < 2; ++nf) {
            int krow = nf * 16 + col;
#pragma unroll
            for (int f = 0; f < 8; ++f) {
                int wb = (f * 32 + quad * 8) ^ swz;            // swizzled u16 off
                bf16x8 bk1 = *(const bf16x8*)&K1c[krow * 256 + wb];
                s1v[nf] = MFMA16(aq1[f], bk1, s1v[nf]);
                bf16x8 bk2 = *(const bf16x8*)&K2c[krow * 256 + wb];
                s2v[nf] = MFMA16(aq2[f], bk2, s2v[nf]);
            }
        }
        __builtin_amdgcn_s_setprio(0);

        // ---- fixed-shift softmax, branch 1 -> P, pull frag ----
#pragma unroll
        for (int r = 0; r < 4; ++r) {
            float p0 = __builtin_amdgcn_exp2f(s1v[0][r] * sc - SH);
            float p1 = __builtin_amdgcn_exp2f(s1v[1][r] * sc - SH);
            l1p[r] += p0 + p1;
            P[(quad * 4 + r) * 36 + col] = f2b(p0);
            P[(quad * 4 + r) * 36 + 16 + col] = f2b(p1);
        }
        bf16x8 p1f = *(const bf16x8*)&P[col * 36 + quad * 8];

        // ---- branch 12 (reuses P region; within-wave DS is in-order) ----
#pragma unroll
        for (int r = 0; r < 4; ++r) {
            float s0 = s1v[0][r] + s2v[0][r];
            float s1x = s1v[1][r] + s2v[1][r];
            float p0 = __builtin_amdgcn_exp2f(s0 * sc - SH);
            float p1 = __builtin_amdgcn_exp2f(s1x * sc - SH);
            l2p[r] += p0 + p1;
            P[(quad * 4 + r) * 36 + col] = f2b(p0);
            P[(quad * 4 + r) * 36 + 16 + col] = f2b(p1);
        }
        bf16x8 p2f = *(const bf16x8*)&P[col * 36 + quad * 8];

        // ---- PV: shared V-frag for both branches ----
        __builtin_amdgcn_s_setprio(1);
#pragma unroll
        for (int cf = 0; cf < 16; ++cf) {
            bf16x8 bv = *(const bf16x8*)&Vc[(cf * 16 + col) * 32 + quad * 8];
            h1[cf] = MFMA16(p1f, bv, h1[cf]);
            h12[cf] = MFMA16(p2f, bv, h12[cf]);
        }
        __builtin_amdgcn_s_setprio(0);
    }

    // ---- finalize: reduce l across the 16 col-lanes of each quad-row ----
    float inv1[4], inv2[4];
#pragma unroll
    for (int r = 0; r < 4; ++r) {
        float s = l1p[r];
        s += __shfl_xor(s, 1); s += __shfl_xor(s, 2);
        s += __shfl_xor(s, 4); s += __shfl_xor(s, 8);
        inv1[r] = 1.f / s;
        float s2x = l2p[r];
        s2x += __shfl_xor(s2x, 1); s2x += __shfl_xor(s2x, 2);
        s2x += __shfl_xor(s2x, 4); s2x += __shfl_xor(s2x, 8);
        inv2[r] = 1.f / s2x;
    }
#pragma unroll
    for (int cf = 0; cf < 16; ++cf)
#pragma unroll
        for (int r = 0; r < 4; ++r) {
            size_t addr = (size_t)(i0 + quad * 4 + r) * 256 + cf * 16 + col;
            H1T[addr] = f2b(h1[cf][r] * inv1[r]);
            H12T[addr] = f2b(h12[cf][r] * inv2[r]);
        }
}

// ---------------------------------------------------------------------------
// kfinal: out[br][b][o][n] = x1 + clamp(bias[o] + sum_c W[o][c] HT[b][n][c])
// 1-D grid 1024, XCD-clustered, block 256, fp32 output.
// ---------------------------------------------------------------------------
__global__ __launch_bounds__(256) void kfinal(
    const float* __restrict__ x1,
    const float* __restrict__ bps, const float* __restrict__ bpc,
    const u16* __restrict__ ws, float* __restrict__ out)
{
    int blk = blockIdx.x;
    int xcd = blk & 7, jj = blk >> 3;        // jj 0..127
    int b = ((jj >> 5) << 3) + xcd;
    int rest = jj & 31;
    int br = rest >> 4, id = rest & 15;
    int mt = id >> 3, nt = id & 7;
    const u16* H = ws + (br ? OFF_H12T : OFF_H1T) + (size_t)b * NC;
    const u16* W = br ? &g_wb[4][0] : &g_wb[3][0];
    const float* bb = br ? bpc : bps;
    const float* X = x1 + (size_t)b * NC;
    float* C = out + (size_t)br * REG + (size_t)b * NC;
    gemm_core(W, H, mt * 128, nt * 128, C, 1024, 1, bb, 1, X, 1);
}

// ---------------------------------------------------------------------------
extern "C" void kernel_launch(void* const* d_in, const int* in_sizes, int n_in,
                              void* d_out, int out_size, void* d_ws, size_t ws_size,
                              hipStream_t stream)
{
    float* out = (float*)d_out;
    u16* ws = (u16*)d_ws;

    if (ws_size < WS_NEED_BYTES) { ksig<<<1, 64, 0, stream>>>(out, 1.0e7f); return; }
    if (n_in != 12 || in_sizes[0] != 8388608 || in_sizes[1] != 8388608 ||
        in_sizes[2] != 65536 || in_sizes[3] != 256 || out_size != 16777216) {
        ksig<<<1, 64, 0, stream>>>(out, 5.0e6f); return;
    }

    const float* x1  = (const float*)d_in[0];
    const float* x2  = (const float*)d_in[1];
    const float* Wq  = (const float*)d_in[2];
    const float* bq  = (const float*)d_in[3];
    const float* Wk  = (const float*)d_in[4];
    const float* bk  = (const float*)d_in[5];
    const float* Wv  = (const float*)d_in[6];
    const float* bv  = (const float*)d_in[7];
    const float* Wps = (const float*)d_in[8];
    const float* bps = (const float*)d_in[9];
    const float* Wpc = (const float*)d_in[10];
    const float* bpc = (const float*)d_in[11];

    kprep<<<320, 256, 0, stream>>>(Wq, Wk, Wv, Wps, Wpc);
    ktrans<<<dim3(16, 4, 64), 256, 0, stream>>>(x1, x2, ws);
    kproj<<<2560, 256, 0, stream>>>(bq, bk, bv, ws);
    kattn<<<256, 512, 0, stream>>>(ws);
    kfinal<<<1024, 256, 0, stream>>>(x1, bps, bpc, ws, out);
}

// Round 5
// 300.113 us; speedup vs baseline: 1.2602x; 1.0954x over previous
//
#include <hip/hip_runtime.h>

// ---------------------------------------------------------------------------
// SpatialSelfCrossAttention  (B=32, C=256, H=W=32, N=1024)
// I/O fp32, internal bf16 MFMA (fp32 accum).
//
// Round-10 changes:
//  * kfinal ELIMINATED: output projections (Wps/Wpc) fused into kattn's
//    epilogue. After the K/V loop, scaled bf16 H is written to LDS (aliasing
//    the dead K/V buffers, rows padded to 264 u16), then each wave computes
//    a 32-out-ch x 128-query tile per branch: A = W rows (L2-resident g_wb),
//    B = H from LDS, D[row=o][col=n] -> coalesced fp32 out stores with
//    clamp + x1 residual (identical math/order to the old kfinal gemm).
//    Saves: kfinal launch + 32MB H write + 32MB H read + 32MB x1 re-read.
//  * ktrans / kproj / kprep / gemm_core unchanged.
// ---------------------------------------------------------------------------

typedef unsigned short u16;
typedef __attribute__((ext_vector_type(8))) short bf16x8;
typedef __attribute__((ext_vector_type(4))) float f32x4;

#define MFMA16(a, b, c) __builtin_amdgcn_mfma_f32_16x16x32_bf16((a), (b), (c), 0, 0, 0)

#define NC 262144ull            // 1024*256
#define REG 8388608ull          // 32*NC
#define OFF_X1T  0ull
#define OFF_X2T  (REG)
#define OFF_Q1T  (2ull*REG)
#define OFF_K1T  (3ull*REG)
#define OFF_Q2T  (4ull*REG)
#define OFF_K2T  (5ull*REG)
#define OFF_V    (6ull*REG)
#define WS_NEED_BYTES (7ull*REG*2)

// bf16 weights: 0 Wq, 1 Wk, 2 Wv, 3 Wps, 4 Wpc  (converted once by kprep)
__device__ __align__(16) u16 g_wb[5][65536];

__device__ __forceinline__ float b2f(u16 u) {
    union { unsigned int i; float f; } v; v.i = ((unsigned int)u) << 16; return v.f;
}
__device__ __forceinline__ u16 f2b(float f) {
    union { float f; unsigned int i; } v; v.f = f;
    unsigned int r = (v.i + 0x7FFFu + ((v.i >> 16) & 1u)) >> 16;
    return (u16)r;
}

// async global->LDS DMA, 16 B per lane. lptr must be wave-uniform; HW adds
// lane*16. gptr is per-lane.
__device__ __forceinline__ void gload16(const u16* g, u16* l) {
    __builtin_amdgcn_global_load_lds(
        (const __attribute__((address_space(1))) void*)g,
        (__attribute__((address_space(3))) void*)l,
        16, 0, 0);
}

__global__ void ksig(float* out, float val) {
    if (threadIdx.x == 0 && blockIdx.x == 0) out[0] = val;
}

// ---------------------------------------------------------------------------
// kprep: 5x 256x256 fp32 weights -> bf16 g_wb. grid 320, block 256.
// ---------------------------------------------------------------------------
__global__ __launch_bounds__(256) void kprep(
    const float* __restrict__ Wq, const float* __restrict__ Wk,
    const float* __restrict__ Wv, const float* __restrict__ Wps,
    const float* __restrict__ Wpc)
{
    int blk = blockIdx.x;
    int w = blk >> 6, j = blk & 63;
    const float* src = (w == 0) ? Wq : (w == 1) ? Wk : (w == 2) ? Wv : (w == 3) ? Wps : Wpc;
    int idx = j * 1024 + threadIdx.x * 4;
    float4 v = *(const float4*)(src + idx);
    ushort4 o;
    o.x = f2b(v.x); o.y = f2b(v.y); o.z = f2b(v.z); o.w = f2b(v.w);
    *(ushort4*)&g_wb[w][idx] = o;
}

// ---------------------------------------------------------------------------
// ktrans: X[b][c][n] fp32 -> XT[b][n][c] bf16. grid (16,4,64), block 256.
// ---------------------------------------------------------------------------
__global__ __launch_bounds__(256) void ktrans(
    const float* __restrict__ x1, const float* __restrict__ x2, u16* __restrict__ ws)
{
    int nt = blockIdx.x, ct = blockIdx.y, bz = blockIdx.z;
    int b = bz >> 1, which = bz & 1;
    const float* X = (which ? x2 : x1) + (size_t)b * NC;
    u16* XT = ws + (which ? OFF_X2T : OFF_X1T) + (size_t)b * NC;
    int c0 = ct * 64, n0 = nt * 64;

    __shared__ __align__(16) u16 tile[64][68];
    int t = threadIdx.x;
    int tn = t & 15, tc = t >> 4;
#pragma unroll
    for (int j = 0; j < 4; ++j) {
        float4 v = *(const float4*)(X + (size_t)(c0 + 4 * tc + j) * 1024 + n0 + 4 * tn);
        u16* d = &tile[4 * tc + j][4 * tn];
        d[0] = f2b(v.x); d[1] = f2b(v.y); d[2] = f2b(v.z); d[3] = f2b(v.w);
    }
    __syncthreads();
    int tcB = t & 15, tnB = t >> 4;
#pragma unroll
    for (int i = 0; i < 4; ++i) {
        ushort4 o;
        o.x = tile[4 * tcB + 0][4 * tnB + i];
        o.y = tile[4 * tcB + 1][4 * tnB + i];
        o.z = tile[4 * tcB + 2][4 * tnB + i];
        o.w = tile[4 * tcB + 3][4 * tnB + i];
        *(ushort4*)(XT + (size_t)(n0 + 4 * tnB + i) * 256 + c0 + 4 * tcB) = o;
    }
}

// ---------------------------------------------------------------------------
// gemm_core v2 (pure bf16, async DMA staging): C[128x128] = A[m][256] *
// B[n][256]^T (+bias, +fp32 residual). Chunk-XOR swizzled LDS slabs.
// ---------------------------------------------------------------------------
__device__ __forceinline__ void gemm_core(
    const u16* __restrict__ A, const u16* __restrict__ B,
    int m0, int n0,
    void* __restrict__ C, int ldc, int cF32,
    const float* __restrict__ bias, int biasPerRow,
    const float* __restrict__ addSrc, int clampH)
{
    __shared__ __align__(16) u16 As[2][4096];   // [buf][128*32]
    __shared__ __align__(16) u16 Bs[2][4096];
    int t = threadIdx.x;
    int lane = t & 63, wave = t >> 6;
    int wm = wave >> 1, wn = wave & 1;
    int col = lane & 15, quad = lane >> 4;

    f32x4 acc[4][4];
#pragma unroll
    for (int i = 0; i < 4; ++i)
#pragma unroll
        for (int j = 0; j < 4; ++j) acc[i][j] = f32x4{0.f, 0.f, 0.f, 0.f};

    int rA = t >> 2;
    int lA = (((t & 3) ^ ((t >> 3) & 3)) << 3);        // u16 offset in row
    const u16* aB = A + (size_t)(m0 + rA) * 256 + lA;
    const u16* bB = B + (size_t)(n0 + rA) * 256 + lA;
    int ldsw = wave * 512;

    int rchunk = ((quad ^ ((col >> 1) & 3)) << 3);

    gload16(aB,          &As[0][ldsw]);
    gload16(aB + 16384,  &As[0][ldsw + 2048]);
    gload16(bB,          &Bs[0][ldsw]);
    gload16(bB + 16384,  &Bs[0][ldsw + 2048]);

    for (int kt = 0; kt < 8; ++kt) {
        int cur = kt & 1;
        __syncthreads();
        if (kt < 7) {
            int off = (kt + 1) * 32;
            gload16(aB + off,          &As[cur ^ 1][ldsw]);
            gload16(aB + off + 16384,  &As[cur ^ 1][ldsw + 2048]);
            gload16(bB + off,          &Bs[cur ^ 1][ldsw]);
            gload16(bB + off + 16384,  &Bs[cur ^ 1][ldsw + 2048]);
        }

        bf16x8 af[4], bf[4];
#pragma unroll
        for (int mf = 0; mf < 4; ++mf)
            af[mf] = *(const bf16x8*)&As[cur][(wm * 64 + mf * 16 + col) * 32 + rchunk];
#pragma unroll
        for (int nf = 0; nf < 4; ++nf)
            bf[nf] = *(const bf16x8*)&Bs[cur][(wn * 64 + nf * 16 + col) * 32 + rchunk];
        __builtin_amdgcn_s_setprio(1);
#pragma unroll
        for (int mf = 0; mf < 4; ++mf)
#pragma unroll
            for (int nf = 0; nf < 4; ++nf)
                acc[mf][nf] = MFMA16(af[mf], bf[nf], acc[mf][nf]);
        __builtin_amdgcn_s_setprio(0);
    }

#pragma unroll
    for (int mf = 0; mf < 4; ++mf)
#pragma unroll
        for (int nf = 0; nf < 4; ++nf) {
            int gm = m0 + wm * 64 + mf * 16 + quad * 4;
            int gn = n0 + wn * 64 + nf * 16 + col;
            float bcol = biasPerRow ? 0.f : bias[gn];
#pragma unroll
            for (int r = 0; r < 4; ++r) {
                int row = gm + r;
                float hv = acc[mf][nf][r] + (biasPerRow ? bias[row] : bcol);
                if (clampH) hv = fminf(fmaxf(hv, -0.05f), 0.05f);
                size_t ci = (size_t)row * ldc + gn;
                float v = hv + (addSrc ? addSrc[ci] : 0.f);
                if (cF32) ((float*)C)[ci] = v;
                else ((u16*)C)[ci] = f2b(v);
            }
        }
}

// ---------------------------------------------------------------------------
// kproj: 5 projections per batch. 1-D grid 2560, XCD-clustered, block 256.
// ---------------------------------------------------------------------------
__global__ __launch_bounds__(256) void kproj(
    const float* __restrict__ bq, const float* __restrict__ bk,
    const float* __restrict__ bv, u16* __restrict__ ws)
{
    int blk = blockIdx.x;
    int xcd = blk & 7, jj = blk >> 3;       // jj 0..319
    int bg = jj / 80, id = jj % 80;
    int b = bg * 8 + xcd;                   // batches serialize per XCD
    const u16* X1T = ws + OFF_X1T + (size_t)b * NC;
    const u16* X2T = ws + OFF_X2T + (size_t)b * NC;
    if (id < 64) {
        int out = id >> 4, tt = id & 15, mt = tt >> 1, nt = tt & 1;
        const u16* A = (out < 2) ? X1T : X2T;
        const u16* W = (out & 1) ? &g_wb[1][0] : &g_wb[0][0];
        const float* bb = (out & 1) ? bk : bq;
        size_t off = (out == 0) ? OFF_Q1T : (out == 1) ? OFF_K1T : (out == 2) ? OFF_Q2T : OFF_K2T;
        u16* C = ws + off + (size_t)b * NC;
        gemm_core(A, W, mt * 128, nt * 128, C, 256, 0, bb, 0, nullptr, 0);
    } else {
        int tt = id - 64, mt = tt >> 3, nt = tt & 7;
        u16* C = ws + OFF_V + (size_t)b * NC;
        gemm_core(&g_wb[2][0], X1T, mt * 128, nt * 128, C, 1024, 0, bv, 1, nullptr, 0);
    }
}

// ---------------------------------------------------------------------------
// kattn v5: grid 256 (XCD-clustered), block 512 = 8 waves x 16 queries.
// Main loop = verified r6 structure (async DMA dbuf, 1 barrier/iter).
// NEW fused epilogue: out = x1 + clamp(bias + Wps/Wpc * H) computed in-block.
//
// LDS (one flat pool, aliased):
//   main loop: K1[2][8192] @0, K2[2][8192] @16384, V[2][8192] @32768,
//              P[8][576] @49152   (total 53760 u16 = 105 KB)
//   epilogue:  HS[128 q][264] @0  (33792 u16 = 66 KB, aliases dead K/V)
// ---------------------------------------------------------------------------
__global__ __launch_bounds__(512, 2) void kattn(
    u16* __restrict__ ws, const float* __restrict__ x1,
    const float* __restrict__ bps, const float* __restrict__ bpc,
    float* __restrict__ out)
{
    int blk = blockIdx.x;
    int xcd = blk & 7, jj = blk >> 3;        // jj 0..31
    int b = ((jj >> 3) << 3) + xcd;          // 4 batch-groups, serialized per XCD
    int qt = jj & 7;                         // 8 q-tiles of 128 queries
    int t = threadIdx.x, lane = t & 63, wave = t >> 6;   // wave 0..7
    int col = lane & 15, quad = lane >> 4;

    const u16* Q1T = ws + OFF_Q1T + (size_t)b * NC;
    const u16* K1T = ws + OFF_K1T + (size_t)b * NC;
    const u16* Q2T = ws + OFF_Q2T + (size_t)b * NC;
    const u16* K2T = ws + OFF_K2T + (size_t)b * NC;
    const u16* V   = ws + OFF_V   + (size_t)b * NC;

    __shared__ __align__(16) u16 SH[53760];
    u16* K1s0 = SH;            // [2][8192]
    u16* K2s0 = SH + 16384;    // [2][8192]
    u16* Vs0  = SH + 32768;    // [2][8192]
    u16* P    = SH + 49152 + wave * 576;

    int i0 = qt * 128 + wave * 16;

    // Q fragments in registers: A[m=col][k = f*32 + quad*8 + j]
    bf16x8 aq1[8], aq2[8];
#pragma unroll
    for (int f = 0; f < 8; ++f) {
        aq1[f] = *(const bf16x8*)(Q1T + (size_t)(i0 + col) * 256 + f * 32 + quad * 8);
        aq2[f] = *(const bf16x8*)(Q2T + (size_t)(i0 + col) * 256 + f * 32 + quad * 8);
    }

    f32x4 h1[16], h12[16];
#pragma unroll
    for (int cf = 0; cf < 16; ++cf) { h1[cf] = f32x4{0.f,0.f,0.f,0.f}; h12[cf] = f32x4{0.f,0.f,0.f,0.f}; }
    float l1p[4], l2p[4];
#pragma unroll
    for (int r = 0; r < 4; ++r) { l1p[r] = 0.f; l2p[r] = 0.f; }

    const float sc = 0.0901684400555602f;   // log2(e)/16
    const float SH_ = 5.770780163555851f;   // 4*log2(e): fixed shift, overflow-safe

    // ---- staging geometry (loop-invariant per thread) ----
    int kr_ = t >> 5;                        // key row, shot 0
    int kwb = (t & 31) << 4;                 // stored byte offset
    int kwl = kwb ^ ((kr_ & 7) << 4);        // logical (source) byte offset
    const u16* k1src = K1T + (size_t)kr_ * 256 + (kwl >> 1);
    const u16* k2src = K2T + (size_t)kr_ * 256 + (kwl >> 1);
    int vrow = t >> 2;                       // channel, shot 0
    int vo = (t & 3) << 3;
    const u16* vsrc = V + (size_t)vrow * 1024 + vo;
    int ldsw = wave * 512;                   // wave-uniform LDS base (u16)

    // ---- prologue: async-stage tile 0 into buffer 0 ----
    gload16(k1src,          K1s0 + ldsw);
    gload16(k1src + 4096,   K1s0 + ldsw + 4096);
    gload16(k2src,          K2s0 + ldsw);
    gload16(k2src + 4096,   K2s0 + ldsw + 4096);
    gload16(vsrc,           Vs0 + ldsw);
    gload16(vsrc + 131072,  Vs0 + ldsw + 4096);

    int swz = (col & 7) << 3;                // read-side XOR, u16 units

    for (int it = 0; it < 32; ++it) {
        int cur = it & 1;
        __syncthreads();   // drains vmcnt (DMA of tile `it` done) + barrier

        // ---- async-stage tile it+1 into the other buffer ----
        if (it < 31) {
            int nxt = (cur ^ 1) * 8192;
            const u16* s1 = k1src + (size_t)(it + 1) * 8192;   // +32 key rows
            const u16* s2 = k2src + (size_t)(it + 1) * 8192;
            const u16* sv = vsrc + (size_t)(it + 1) * 32;      // +32 keys
            gload16(s1,          K1s0 + nxt + ldsw);
            gload16(s1 + 4096,   K1s0 + nxt + ldsw + 4096);
            gload16(s2,          K2s0 + nxt + ldsw);
            gload16(s2 + 4096,   K2s0 + nxt + ldsw + 4096);
            gload16(sv,          Vs0 + nxt + ldsw);
            gload16(sv + 131072, Vs0 + nxt + ldsw + 4096);
        }

        const u16* K1c = K1s0 + cur * 8192;
        const u16* K2c = K2s0 + cur * 8192;
        const u16* Vc  = Vs0 + cur * 8192;

        // ---- QK: S1, S2 : D[row=quad*4+r (query)][col (key)] ----
        f32x4 s1v[2], s2v[2];
        s1v[0] = s1v[1] = s2v[0] = s2v[1] = f32x4{0.f,0.f,0.f,0.f};
        __builtin_amdgcn_s_setprio(1);
#pragma unroll
        for (int nf = 0; nf < 2; ++nf) {
            int krow = nf * 16 + col;
#pragma unroll
            for (int f = 0; f < 8; ++f) {
                int wb = (f * 32 + quad * 8) ^ swz;            // swizzled u16 off
                bf16x8 bk1 = *(const bf16x8*)&K1c[krow * 256 + wb];
                s1v[nf] = MFMA16(aq1[f], bk1, s1v[nf]);
                bf16x8 bk2 = *(const bf16x8*)&K2c[krow * 256 + wb];
                s2v[nf] = MFMA16(aq2[f], bk2, s2v[nf]);
            }
        }
        __builtin_amdgcn_s_setprio(0);

        // ---- fixed-shift softmax, branch 1 -> P, pull frag ----
#pragma unroll
        for (int r = 0; r < 4; ++r) {
            float p0 = __builtin_amdgcn_exp2f(s1v[0][r] * sc - SH_);
            float p1 = __builtin_amdgcn_exp2f(s1v[1][r] * sc - SH_);
            l1p[r] += p0 + p1;
            P[(quad * 4 + r) * 36 + col] = f2b(p0);
            P[(quad * 4 + r) * 36 + 16 + col] = f2b(p1);
        }
        bf16x8 p1f = *(const bf16x8*)&P[col * 36 + quad * 8];

        // ---- branch 12 (reuses P region; within-wave DS is in-order) ----
#pragma unroll
        for (int r = 0; r < 4; ++r) {
            float s0 = s1v[0][r] + s2v[0][r];
            float s1x = s1v[1][r] + s2v[1][r];
            float p0 = __builtin_amdgcn_exp2f(s0 * sc - SH_);
            float p1 = __builtin_amdgcn_exp2f(s1x * sc - SH_);
            l2p[r] += p0 + p1;
            P[(quad * 4 + r) * 36 + col] = f2b(p0);
            P[(quad * 4 + r) * 36 + 16 + col] = f2b(p1);
        }
        bf16x8 p2f = *(const bf16x8*)&P[col * 36 + quad * 8];

        // ---- PV: shared V-frag for both branches ----
        __builtin_amdgcn_s_setprio(1);
#pragma unroll
        for (int cf = 0; cf < 16; ++cf) {
            bf16x8 bv = *(const bf16x8*)&Vc[(cf * 16 + col) * 32 + quad * 8];
            h1[cf] = MFMA16(p1f, bv, h1[cf]);
            h12[cf] = MFMA16(p2f, bv, h12[cf]);
        }
        __builtin_amdgcn_s_setprio(0);
    }

    // ---- finalize: reduce l across the 16 col-lanes of each quad-row ----
    float inv1[4], inv2[4];
#pragma unroll
    for (int r = 0; r < 4; ++r) {
        float s = l1p[r];
        s += __shfl_xor(s, 1); s += __shfl_xor(s, 2);
        s += __shfl_xor(s, 4); s += __shfl_xor(s, 8);
        inv1[r] = 1.f / s;
        float s2x = l2p[r];
        s2x += __shfl_xor(s2x, 1); s2x += __shfl_xor(s2x, 2);
        s2x += __shfl_xor(s2x, 4); s2x += __shfl_xor(s2x, 8);
        inv2[r] = 1.f / s2x;
    }

    // ---- fused output projections: out = x1 + clamp(bias + W * H) ----
    // HS: [128 q][264] u16, aliases dead K/V buffers.
    u16* HS = SH;
    const int HROW = 264;
    const float* x1b = x1 + (size_t)b * NC;

    // per-wave out-proj: o-range = wave*32..+31, all 128 block queries.
    auto outproj = [&](const u16* __restrict__ W, const float* __restrict__ bb,
                       float* __restrict__ outp) {
        f32x4 oacc[2][8];
#pragma unroll
        for (int mf = 0; mf < 2; ++mf)
#pragma unroll
            for (int nf = 0; nf < 8; ++nf) oacc[mf][nf] = f32x4{0.f,0.f,0.f,0.f};
#pragma unroll
        for (int kf = 0; kf < 8; ++kf) {
            bf16x8 hb[8];
#pragma unroll
            for (int nf = 0; nf < 8; ++nf)
                hb[nf] = *(const bf16x8*)&HS[(nf * 16 + col) * HROW + kf * 32 + quad * 8];
#pragma unroll
            for (int mf = 0; mf < 2; ++mf) {
                bf16x8 wf = *(const bf16x8*)&W[(wave * 32 + mf * 16 + col) * 256 + kf * 32 + quad * 8];
#pragma unroll
                for (int nf = 0; nf < 8; ++nf)
                    oacc[mf][nf] = MFMA16(wf, hb[nf], oacc[mf][nf]);
            }
        }
#pragma unroll
        for (int mf = 0; mf < 2; ++mf)
#pragma unroll
            for (int r = 0; r < 4; ++r) {
                int o = wave * 32 + mf * 16 + quad * 4 + r;
                float bo = bb[o];
#pragma unroll
                for (int nf = 0; nf < 8; ++nf) {
                    int n = qt * 128 + nf * 16 + col;
                    size_t ci = (size_t)o * 1024 + n;
                    float hv = oacc[mf][nf][r] + bo;
                    hv = fminf(fmaxf(hv, -0.05f), 0.05f);
                    outp[ci] = hv + x1b[ci];
                }
            }
    };

    __syncthreads();    // all waves done with K/V LDS
#pragma unroll
    for (int cf = 0; cf < 16; ++cf)
#pragma unroll
        for (int r = 0; r < 4; ++r)
            HS[(wave * 16 + quad * 4 + r) * HROW + cf * 16 + col] = f2b(h1[cf][r] * inv1[r]);
    __syncthreads();
    outproj(&g_wb[3][0], bps, out + (size_t)b * NC);
    __syncthreads();    // out1 reads done; safe to overwrite HS
#pragma unroll
    for (int cf = 0; cf < 16; ++cf)
#pragma unroll
        for (int r = 0; r < 4; ++r)
            HS[(wave * 16 + quad * 4 + r) * HROW + cf * 16 + col] = f2b(h12[cf][r] * inv2[r]);
    __syncthreads();
    outproj(&g_wb[4][0], bpc, out + REG + (size_t)b * NC);
}

// ---------------------------------------------------------------------------
extern "C" void kernel_launch(void* const* d_in, const int* in_sizes, int n_in,
                              void* d_out, int out_size, void* d_ws, size_t ws_size,
                              hipStream_t stream)
{
    float* out = (float*)d_out;
    u16* ws = (u16*)d_ws;

    if (ws_size < WS_NEED_BYTES) { ksig<<<1, 64, 0, stream>>>(out, 1.0e7f); return; }
    if (n_in != 12 || in_sizes[0] != 8388608 || in_sizes[1] != 8388608 ||
        in_sizes[2] != 65536 || in_sizes[3] != 256 || out_size != 16777216) {
        ksig<<<1, 64, 0, stream>>>(out, 5.0e6f); return;
    }

    const float* x1  = (const float*)d_in[0];
    const float* x2  = (const float*)d_in[1];
    const float* Wq  = (const float*)d_in[2];
    const float* bq  = (const float*)d_in[3];
    const float* Wk  = (const float*)d_in[4];
    const float* bk  = (const float*)d_in[5];
    const float* Wv  = (const float*)d_in[6];
    const float* bv  = (const float*)d_in[7];
    const float* Wps = (const float*)d_in[8];
    const float* bps = (const float*)d_in[9];
    const float* Wpc = (const float*)d_in[10];
    const float* bpc = (const float*)d_in[11];

    kprep<<<320, 256, 0, stream>>>(Wq, Wk, Wv, Wps, Wpc);
    ktrans<<<dim3(16, 4, 64), 256, 0, stream>>>(x1, x2, ws);
    kproj<<<2560, 256, 0, stream>>>(bq, bk, bv, ws);
    kattn<<<256, 512, 0, stream>>>(ws, x1, bps, bpc, out);
}